// Round 5
// baseline (130.012 us; speedup 1.0000x reference)
//
#include <hip/hip_runtime.h>
#include <cstdint>
#include <cstddef>
#include <math.h>

// B=2, L=2048, E=1024, H=16, D=64
#define BB 2
#define LL 2048
#define EE 1024
#define HH 16
#define DD 64
#define MM (BB*LL)

typedef short short8 __attribute__((ext_vector_type(8)));
typedef float f32x4 __attribute__((ext_vector_type(4)));
typedef float f32x16 __attribute__((ext_vector_type(16)));

#define GPTR __attribute__((address_space(1)))
#define LPTR __attribute__((address_space(3)))

__device__ __forceinline__ unsigned short f32_bf16(float f) {
  union { float f; unsigned u; } c; c.f = f;
  c.u += 0x7fffu + ((c.u >> 16) & 1u);
  return (unsigned short)(c.u >> 16);
}

__device__ __forceinline__ unsigned pk_bf16(float lo, float hi) {
  unsigned r;
  asm("v_cvt_pk_bf16_f32 %0, %1, %2" : "=v"(r) : "v"(lo), "v"(hi));
  return r;
}
// v_permlane32_swap_b32 vdst, vsrc:
//   new vdst = [old vdst lanes 0-31 | old vsrc lanes 0-31]
//   new vsrc = [old vdst lanes 32-63 | old vsrc lanes 32-63]
// Operands must be DISTINCT SSA values (else regalloc may alias them).
__device__ __forceinline__ void swap32(unsigned &a, unsigned &b) {
  asm("v_permlane32_swap_b32 %0, %1" : "+v"(a), "+v"(b));
}
__device__ __forceinline__ f32x16 zero16() {
  f32x16 v;
  #pragma unroll
  for (int e = 0; e < 16; ++e) v[e] = 0.f;
  return v;
}

// ---------------- fp32 -> bf16 conversion (x + 4 weights fused) ----------------
__global__ void cvt_all(const float* __restrict__ x,  const float* __restrict__ wq,
                        const float* __restrict__ wk, const float* __restrict__ wv,
                        const float* __restrict__ wo,
                        unsigned short* __restrict__ xb,  unsigned short* __restrict__ wqb,
                        unsigned short* __restrict__ wkb, unsigned short* __restrict__ wvb,
                        unsigned short* __restrict__ wob)
{
  int i = (blockIdx.x * 256 + threadIdx.x) * 4;
  if (i >= MM * EE + 4 * EE * EE) return;
  const float* s; unsigned short* d; int off;
  if (i < MM * EE) { s = x; d = xb; off = i; }
  else {
    int k = i - MM * EE;
    int w = k >> 20;               // EE*EE = 1<<20
    off = k & (EE * EE - 1);
    s = (w == 0) ? wq : (w == 1) ? wk : (w == 2) ? wv : wo;
    d = (w == 0) ? wqb : (w == 1) ? wkb : (w == 2) ? wvb : wob;
  }
  float4 v = *(const float4*)(s + off);
  union { unsigned short s[4]; uint2 u; } o;
  o.s[0] = f32_bf16(v.x); o.s[1] = f32_bf16(v.y);
  o.s[2] = f32_bf16(v.z); o.s[3] = f32_bf16(v.w);
  *(uint2*)(d + off) = o.u;
}

// ---------------- 128x128 bf16 GEMM (NT: A MxK, W NxK) ----------------
// MODE 0: z=0: Q -> (B,H,L,D), *mask*(1/sqrt(D))*log2(e); z=1: K -> (B,H,L,D), *mask;
//         z=2: V^T -> (B,H,D,L), *mask.
// MODE 1: out = A @ W0^T + bias, fp32 row-major.
template<int MODE>
__global__ __launch_bounds__(256, 2)
void gemm128(const unsigned short* __restrict__ A,
             const unsigned short* __restrict__ W0,
             const unsigned short* __restrict__ W1,
             const unsigned short* __restrict__ W2,
             const float* __restrict__ mask,
             const float* __restrict__ bias,
             unsigned short* __restrict__ O0,
             unsigned short* __restrict__ O1,
             unsigned short* __restrict__ O2,
             float* __restrict__ OF)
{
  constexpr int K = EE;
  const int tid = threadIdx.x;
  const int lane = tid & 63;
  const int wid = tid >> 6;
  const int g = lane >> 4, li = lane & 15;
  const int m0 = blockIdx.y * 128;
  const int n0 = blockIdx.x * 128;
  const int z = blockIdx.z;

  const unsigned short* Wp = W0;
  if (MODE == 0) Wp = (z == 0) ? W0 : ((z == 1) ? W1 : W2);

  __shared__ unsigned short As[128 * 64];
  __shared__ unsigned short Bs[128 * 64];

  f32x4 acc[4][4];
  f32x4 zero = {0.f, 0.f, 0.f, 0.f};
  #pragma unroll
  for (int i = 0; i < 4; ++i)
    #pragma unroll
    for (int j = 0; j < 4; ++j) acc[i][j] = zero;

  const int wm = (wid >> 1) * 64;
  const int wn = (wid & 1) * 64;

  for (int kt = 0; kt < K; kt += 64) {
    #pragma unroll
    for (int j = 0; j < 4; ++j) {
      int c = j * 256 + tid;
      int row = c >> 3;
      int lcol = ((c & 7) * 16) ^ ((row & 7) << 4);
      __builtin_amdgcn_global_load_lds(
        (const GPTR void*)((const char*)(A + (size_t)(m0 + row) * K + kt) + lcol),
        (LPTR void*)((char*)As + c * 16), 16, 0, 0);
      __builtin_amdgcn_global_load_lds(
        (const GPTR void*)((const char*)(Wp + (size_t)(n0 + row) * K + kt) + lcol),
        (LPTR void*)((char*)Bs + c * 16), 16, 0, 0);
    }
    __syncthreads();

    #pragma unroll
    for (int kk = 0; kk < 2; ++kk) {
      short8 a[4], b[4];
      const int colb = (kk * 32 + g * 8) * 2;
      #pragma unroll
      for (int i = 0; i < 4; ++i) {
        int ar = wm + i * 16 + li;
        a[i] = *(const short8*)((const char*)As + ar * 128 + (colb ^ ((ar & 7) << 4)));
        int br = wn + i * 16 + li;
        b[i] = *(const short8*)((const char*)Bs + br * 128 + (colb ^ ((br & 7) << 4)));
      }
      #pragma unroll
      for (int i = 0; i < 4; ++i)
        #pragma unroll
        for (int j = 0; j < 4; ++j)
          acc[i][j] = __builtin_amdgcn_mfma_f32_16x16x32_bf16(a[i], b[j], acc[i][j], 0, 0, 0);
    }
    __syncthreads();
  }

  // epilogue. C/D layout: col = li, row = g*4 + r
  if (MODE == 0) {
    if (z == 2) {
      #pragma unroll
      for (int i = 0; i < 4; ++i) {
        int mbase = m0 + wm + i * 16 + g * 4;
        int bb2 = mbase >> 11;
        int l0  = mbase & (LL - 1);
        float mk[4];
        #pragma unroll
        for (int r = 0; r < 4; ++r) mk[r] = mask[mbase + r];
        #pragma unroll
        for (int j = 0; j < 4; ++j) {
          int n = n0 + wn + j * 16 + li;
          int h2 = n >> 6, dd2 = n & 63;
          union { unsigned short s[4]; uint2 u; } o;
          #pragma unroll
          for (int r = 0; r < 4; ++r) o.s[r] = f32_bf16(acc[i][j][r] * mk[r]);
          *(uint2*)(O2 + ((size_t)(bb2 * HH + h2) * DD + dd2) * LL + l0) = o.u;
        }
      }
    } else {
      unsigned short* Op = (z == 0) ? O0 : O1;
      // z==0: 1/sqrt(64) * log2(e) folded into Q (softmax runs in exp2 domain)
      const float sc = (z == 0) ? 0.125f * 1.44269504088896f : 1.0f;
      #pragma unroll
      for (int i = 0; i < 4; ++i) {
        #pragma unroll
        for (int r = 0; r < 4; ++r) {
          int m = m0 + wm + i * 16 + g * 4 + r;
          float mk = mask[m] * sc;
          int bb = m >> 11;
          int l  = m & (LL - 1);
          #pragma unroll
          for (int j = 0; j < 4; ++j) {
            int n = n0 + wn + j * 16 + li;
            int h = n >> 6, d = n & 63;
            size_t off = (((size_t)(bb * HH + h)) * LL + l) * DD + d;
            Op[off] = f32_bf16(acc[i][j][r] * mk);
          }
        }
      }
    }
  } else {
    #pragma unroll
    for (int i = 0; i < 4; ++i) {
      #pragma unroll
      for (int j = 0; j < 4; ++j) {
        int n = n0 + wn + j * 16 + li;
        float bv = bias[n];
        #pragma unroll
        for (int r = 0; r < 4; ++r) {
          int m = m0 + wm + i * 16 + g * 4 + r;
          OF[(size_t)m * EE + n] = acc[i][j][r] + bv;
        }
      }
    }
  }
}

// ---------------- causal flash attention, swapped-operand form ----------------
// QBLK=64 (2 waves x 32 q-rows), KVBLK=64, dbuf LDS, 1 barrier/tile.
// All 16 ds_read_b128 batched at tile top (latency paid once), then reg-only compute.
// Softmax in exp2 domain (log2e pre-folded into Q).
__global__ __launch_bounds__(128, 2)
void attn2(const unsigned short* __restrict__ Q,
           const unsigned short* __restrict__ K,
           const unsigned short* __restrict__ VT,
           unsigned short* __restrict__ Y)
{
  const int tid = threadIdx.x, lane = tid & 63, wq = tid >> 6;
  const int l31 = lane & 31, hi = lane >> 5;

  const int id = blockIdx.x;
  const int bh_lo = id & 7;
  const int r_ = id >> 3;
  const int bh = (r_ & 3) * 8 + bh_lo;      // 4 heads per XCD
  const int qt = 31 - (r_ >> 2);            // heavy q-tiles first
  const int q0 = qt * 64;
  const int b = bh >> 4, h = bh & (HH - 1);
  const size_t kbase = (size_t)bh * LL * DD;

  __shared__ unsigned short Ks[2][64 * 64];
  __shared__ unsigned short Vs[2][64 * 64];

  const unsigned short* Kg  = K + kbase;
  const unsigned short* VTg = VT + kbase;   // (D,L) within head

  const int qrow = q0 + wq * 32 + l31;
  const int qmin = q0 + wq * 32;

  short8 qf[4];
  {
    const unsigned short* Qr = Q + kbase + (size_t)qrow * DD + hi * 8;
    #pragma unroll
    for (int kc = 0; kc < 4; ++kc) qf[kc] = *(const short8*)(Qr + kc * 16);
  }

  f32x16 ot0 = zero16(), ot1 = zero16();
  float m = -INFINITY, lsum = 0.f;

  const int nt = qt + 1;

  auto stage = [&](int buf, int t2) {
    const int kv0s = t2 << 6;
    #pragma unroll
    for (int u = 0; u < 4; ++u) {
      int c = u * 128 + tid;                // 16B chunk 0..511
      int row = c >> 3;
      int cb = (c & 7) * 16;
      int scol = cb ^ ((row & 7) << 4);
      __builtin_amdgcn_global_load_lds(
        (const GPTR void*)((const char*)(Kg + (size_t)(kv0s + row) * DD) + scol),
        (LPTR void*)((char*)Ks[buf] + c * 16), 16, 0, 0);
      __builtin_amdgcn_global_load_lds(
        (const GPTR void*)((const char*)(VTg + (size_t)row * LL + kv0s) + scol),
        (LPTR void*)((char*)Vs[buf] + c * 16), 16, 0, 0);
    }
  };

  stage(0, 0);
  int cur = 0;

  const int cb0 = hi * 16;
  const int r0 = l31, r1 = 32 + l31;
  const int swz = ((l31 & 7) << 4);

  for (int t = 0; t < nt; ++t) {
    __syncthreads();                       // buf[cur] staged
    const char* Kb_ = (const char*)Ks[cur];
    const char* Vb_ = (const char*)Vs[cur];

    // ---- batched LDS reads: all operands for this tile ----
    short8 k0[4], k1[4], v0[4], v1[4];
    #pragma unroll
    for (int kc = 0; kc < 4; ++kc) {
      int cb = (kc * 32 + cb0) ^ swz;
      k0[kc] = *(const short8*)(Kb_ + r0 * 128 + cb);
      k1[kc] = *(const short8*)(Kb_ + r1 * 128 + cb);
      v0[kc] = *(const short8*)(Vb_ + r0 * 128 + cb);
      v1[kc] = *(const short8*)(Vb_ + r1 * 128 + cb);
    }
    if (t + 1 < nt) stage(cur ^ 1, t + 1); // next tile in flight during compute
    __builtin_amdgcn_sched_barrier(0);     // all loads issued before compute

    const int kv0 = t << 6;
    // s1 covers kv0+32..kv0+63; needed iff some lane's qrow >= kv0+32
    const bool need1 = (kv0 + 32 <= qmin + 31);

    // ---- S^T = K · Q^T (log2 units) ----
    f32x16 s0 = zero16(), s1 = zero16();
    __builtin_amdgcn_s_setprio(1);
    if (need1) {
      #pragma unroll
      for (int kc = 0; kc < 4; ++kc) {
        s0 = __builtin_amdgcn_mfma_f32_32x32x16_bf16(k0[kc], qf[kc], s0, 0, 0, 0);
        s1 = __builtin_amdgcn_mfma_f32_32x32x16_bf16(k1[kc], qf[kc], s1, 0, 0, 0);
      }
    } else {
      #pragma unroll
      for (int kc = 0; kc < 4; ++kc)
        s0 = __builtin_amdgcn_mfma_f32_32x32x16_bf16(k0[kc], qf[kc], s0, 0, 0, 0);
    }
    __builtin_amdgcn_s_setprio(0);

    // ---- causal mask (diagonal tiles only) ----
    if (kv0 + 63 > qmin) {
      #pragma unroll
      for (int rg = 0; rg < 4; ++rg)
        #pragma unroll
        for (int e = 0; e < 4; ++e) {
          int kvg = kv0 + rg * 8 + hi * 4 + e;
          if (kvg > qrow)                s0[rg * 4 + e] = -INFINITY;
          if (need1 && kvg + 32 > qrow)  s1[rg * 4 + e] = -INFINITY;
        }
    }

    // ---- online softmax (exp2 domain): tree reduce + one cross-half shfl ----
    float red[16];
    #pragma unroll
    for (int e = 0; e < 16; ++e) red[e] = need1 ? fmaxf(s0[e], s1[e]) : s0[e];
    #pragma unroll
    for (int st = 8; st >= 1; st >>= 1)
      #pragma unroll
      for (int e = 0; e < 8; ++e) if (e < st) red[e] = fmaxf(red[e], red[e + st]);
    float mv = red[0];
    mv = fmaxf(mv, __shfl_xor(mv, 32, 64));

    if (!__all(mv <= m + 8.0f)) {          // T13 defer-max (P bounded by 2^8)
      float mnew = fmaxf(m, mv);
      float al = exp2f(m - mnew);
      m = mnew;
      lsum *= al;
      #pragma unroll
      for (int e = 0; e < 16; ++e) { ot0[e] *= al; ot1[e] *= al; }
    }

    float rs;
    {
      float ra[16];
      #pragma unroll
      for (int e = 0; e < 16; ++e) { s0[e] = exp2f(s0[e] - m); ra[e] = s0[e]; }
      if (need1) {
        #pragma unroll
        for (int e = 0; e < 16; ++e) { s1[e] = exp2f(s1[e] - m); ra[e] += s1[e]; }
      }
      #pragma unroll
      for (int st = 8; st >= 1; st >>= 1)
        #pragma unroll
        for (int e = 0; e < 8; ++e) if (e < st) ra[e] += ra[e + st];
      rs = ra[0];
    }
    rs += __shfl_xor(rs, 32, 64);
    lsum += rs;

    // ---- P fragments: cvt_pk + permlane32_swap (T12) ----
    auto mkfrag = [&](const f32x16& sv, int base) -> short8 {
      unsigned a0 = pk_bf16(sv[base + 0], sv[base + 1]);
      unsigned a1 = pk_bf16(sv[base + 2], sv[base + 3]);
      unsigned b0 = pk_bf16(sv[base + 4], sv[base + 5]);
      unsigned b1 = pk_bf16(sv[base + 6], sv[base + 7]);
      swap32(a0, b0);
      swap32(a1, b1);
      union { unsigned u[4]; short8 s; } f;
      f.u[0] = a0; f.u[1] = a1; f.u[2] = b0; f.u[3] = b1;
      return f.s;
    };
    short8 pf[4];
    pf[0] = mkfrag(s0, 0); pf[1] = mkfrag(s0, 8);
    if (need1) { pf[2] = mkfrag(s1, 0); pf[3] = mkfrag(s1, 8); }

    // ---- O^T += V^T · P^T ----
    __builtin_amdgcn_s_setprio(1);
    if (need1) {
      #pragma unroll
      for (int kc = 0; kc < 4; ++kc) {
        ot0 = __builtin_amdgcn_mfma_f32_32x32x16_bf16(v0[kc], pf[kc], ot0, 0, 0, 0);
        ot1 = __builtin_amdgcn_mfma_f32_32x32x16_bf16(v1[kc], pf[kc], ot1, 0, 0, 0);
      }
    } else {
      #pragma unroll
      for (int kc = 0; kc < 2; ++kc) {
        ot0 = __builtin_amdgcn_mfma_f32_32x32x16_bf16(v0[kc], pf[kc], ot0, 0, 0, 0);
        ot1 = __builtin_amdgcn_mfma_f32_32x32x16_bf16(v1[kc], pf[kc], ot1, 0, 0, 0);
      }
    }
    __builtin_amdgcn_s_setprio(0);
    cur ^= 1;
  }

  // ---- epilogue: Y (B,L,E) bf16, packed 8B stores ----
  float inv = 1.0f / lsum;
  unsigned short* Yr = Y + ((size_t)b * LL + qrow) * EE + h * DD;
  #pragma unroll
  for (int rg = 0; rg < 4; ++rg) {
    union { unsigned short s[4]; uint2 u; } o0, o1;
    #pragma unroll
    for (int e = 0; e < 4; ++e) {
      o0.s[e] = f32_bf16(ot0[rg * 4 + e] * inv);
      o1.s[e] = f32_bf16(ot1[rg * 4 + e] * inv);
    }
    *(uint2*)(Yr + rg * 8 + hi * 4) = o0.u;
    *(uint2*)(Yr + 32 + rg * 8 + hi * 4) = o1.u;
  }
}

// ---------------- launch ----------------
extern "C" void kernel_launch(void* const* d_in, const int* in_sizes, int n_in,
                              void* d_out, int out_size, void* d_ws, size_t ws_size,
                              hipStream_t stream) {
  const float* x    = (const float*)d_in[0];
  const float* mask = (const float*)d_in[1];
  const float* Wq   = (const float*)d_in[2];
  const float* Wk   = (const float*)d_in[3];
  const float* Wv   = (const float*)d_in[4];
  const float* Wo   = (const float*)d_in[5];
  const float* bo   = (const float*)d_in[6];
  float* out = (float*)d_out;

  char* ws = (char*)d_ws;
  unsigned short* xb  = (unsigned short*)(ws);
  unsigned short* wqb = (unsigned short*)(ws + ((size_t)8  << 20));
  unsigned short* wkb = (unsigned short*)(ws + ((size_t)10 << 20));
  unsigned short* wvb = (unsigned short*)(ws + ((size_t)12 << 20));
  unsigned short* wob = (unsigned short*)(ws + ((size_t)14 << 20));
  unsigned short* Qb  = (unsigned short*)(ws + ((size_t)16 << 20));
  unsigned short* Kb  = (unsigned short*)(ws + ((size_t)24 << 20));
  unsigned short* VTb = (unsigned short*)(ws + ((size_t)32 << 20));
  unsigned short* Yb  = (unsigned short*)(ws + ((size_t)40 << 20));

  cvt_all<<<8192, 256, 0, stream>>>(x, Wq, Wk, Wv, Wo, xb, wqb, wkb, wvb, wob);

  gemm128<0><<<dim3(EE / 128, MM / 128, 3), 256, 0, stream>>>(
      xb, wqb, wkb, wvb, mask, nullptr, Qb, Kb, VTb, nullptr);

  attn2<<<dim3(1024), 128, 0, stream>>>(Qb, Kb, VTb, Yb);

  gemm128<1><<<dim3(EE / 128, MM / 128, 1), 256, 0, stream>>>(
      Yb, wob, nullptr, nullptr, nullptr, bo, nullptr, nullptr, nullptr, out);
}